// Round 18
// baseline (81.124 us; speedup 1.0000x reference)
//
#include <hip/hip_runtime.h>
#include <hip/hip_bf16.h>

#define KTOT   25088          // 2 * 256 * 49
#define HALF_K 12544
#define HID    512
#define SPLITK 14
#define KCHUNK (KTOT/SPLITK)  // 1792 = 28 * 64
#define NTILE  28             // BK=64 tiles per k-chunk

typedef __attribute__((ext_vector_type(8))) short short8;
typedef __attribute__((ext_vector_type(4))) float f32x4;

__device__ __forceinline__ unsigned short f2bf(float x) {
  __hip_bfloat16 h = __float2bfloat16(x);
  return *reinterpret_cast<unsigned short*>(&h);
}
__device__ __forceinline__ float bf2f(unsigned short u) {
  return __uint_as_float((unsigned)u << 16);
}

__device__ __forceinline__ void gl_lds16(const __hip_bfloat16* g, __hip_bfloat16* l) {
  __builtin_amdgcn_global_load_lds((const __attribute__((address_space(1))) void*)g,
                                   (__attribute__((address_space(3))) void*)l, 16, 0, 0);
}

// ---------- feats [C,H,W] fp32 -> fts bf16 [map][cslice][cell][64ch] (slice-major) ----------
__global__ __launch_bounds__(256) void k_tfeat(const float* __restrict__ f1,
                                               const float* __restrict__ f2,
                                               __hip_bfloat16* __restrict__ fts) {
  __shared__ float tile[64][65];
  const int ct = blockIdx.x, yxt = blockIdx.y, map = blockIdx.z;
  const float* src = map ? f2 : f1;
  const int t = threadIdx.x, t4 = t >> 6, tl = t & 63;
#pragma unroll
  for (int pass = 0; pass < 16; ++pass) {
    int cl = pass * 4 + t4;
    tile[cl][tl] = src[(ct * 64 + cl) * 1024 + yxt * 64 + tl];
  }
  __syncthreads();
#pragma unroll
  for (int pass = 0; pass < 16; ++pass) {
    int yl = pass * 4 + t4;
    fts[((size_t)(map * 4 + ct) * 1024 + yxt * 64 + yl) * 64 + tl] =
        __float2bfloat16(tile[tl][yl]);
  }
}

// ---------- W1 [25088][512] -> W1t bf16 [512][25088'] with k' = map*12544 + p*256 + c ----------
__global__ __launch_bounds__(256) void k_tw1(const float* __restrict__ W1,
                                             __hip_bfloat16* __restrict__ W1t) {
  __shared__ float tile[64][65];
  const int ct = blockIdx.x & 3, jt = blockIdx.x >> 2;
  const int p = blockIdx.y, map = blockIdx.z;
  const int t = threadIdx.x, t4 = t >> 6, tl = t & 63;
#pragma unroll
  for (int pass = 0; pass < 16; ++pass) {
    int cl = pass * 4 + t4;
    int c = ct * 64 + cl;
    size_t krow = (size_t)map * HALF_K + (size_t)c * 49 + p;
    tile[cl][tl] = W1[krow * HID + jt * 64 + tl];
  }
  __syncthreads();
#pragma unroll
  for (int pass = 0; pass < 16; ++pass) {
    int jl = pass * 4 + t4;
    int j = jt * 64 + jl;
    W1t[(size_t)j * KTOT + (size_t)map * HALF_K + p * 256 + ct * 64 + tl] =
        __float2bfloat16(tile[tl][jl]);
  }
}

// ---------- RoIAlign: slice-resident LDS gather ----------
// grid 256 = 8 slices x 32 box-groups; block: 128 KB slice in LDS, 32 boxes
// thread: b = t>>3 (box), cg = t&7 (8 channels); gathers are ds_read_b128, conflict-free
__global__ __launch_bounds__(256) void k_roi(const __hip_bfloat16* __restrict__ fts,
                                             const float* __restrict__ props,
                                             __hip_bfloat16* __restrict__ A) {
  __shared__ __align__(16) __hip_bfloat16 feat[1024 * 64];   // 128 KB
  __shared__ int   s_yoff[32][7][3];
  __shared__ float s_wy[32][7][3];
  __shared__ int   s_xoff[32][7][3];
  __shared__ float s_wx[32][7][3];
  const int t = threadIdx.x;
  const int slice = blockIdx.x & 7;          // map = slice>>2, c0 = (slice&3)*64
  const int grp = blockIdx.x >> 3;           // boxes grp*32 .. grp*32+31
  // stage 128 KB contiguous
  {
    const __hip_bfloat16* src = fts + (size_t)slice * 65536 + t * 8;
    __hip_bfloat16* dst = &feat[t * 8];
#pragma unroll
    for (int i = 0; i < 32; ++i)
      gl_lds16(src + i * 2048, dst + i * 2048);
  }
  // tables: 32 boxes x 14 axes (7 y + 7 x), merged <=3 corners per axis
  const float sc = 1.0f / 32.0f;
  for (int j = t; j < 448; j += 256) {
    const int b = j / 14, ax = j % 14;
    const int n = grp * 32 + b;
    float bx1 = props[n * 4 + 0] * sc, by1 = props[n * 4 + 1] * sc;
    float bx2 = props[n * 4 + 2] * sc, by2 = props[n * 4 + 3] * sc;
    float bw = fmaxf(bx2 - bx1, 1.f) * (1.f / 7.f);
    float bh = fmaxf(by2 - by1, 1.f) * (1.f / 7.f);
    const bool isY = (ax < 7);
    const int i = isY ? ax : (ax - 7);
    const float start = isY ? by1 : bx1;
    const float bs = isY ? bh : bw;
    int idxs[4]; float ws[4];
#pragma unroll
    for (int ssub = 0; ssub < 2; ++ssub) {
      float o = start + (float)i * bs + ((float)ssub + 0.5f) * bs * 0.5f;
      float v = (o >= -1.f && o <= 32.f) ? 1.f : 0.f;
      float oc = fminf(fmaxf(o, 0.f), 31.f);
      int i0 = (int)oc;
      int i1 = min(i0 + 1, 31);
      float l = oc - (float)i0;
      idxs[ssub * 2 + 0] = i0; ws[ssub * 2 + 0] = v * (1.f - l);
      idxs[ssub * 2 + 1] = i1; ws[ssub * 2 + 1] = v * l;
    }
    int mi[3] = {0, 0, 0}; float mw[3] = {0.f, 0.f, 0.f}; int cnt = 0;
#pragma unroll
    for (int e = 0; e < 4; ++e) {
      if (ws[e] != 0.f) {
        bool found = false;
#pragma unroll
        for (int f = 0; f < 3; ++f)
          if (f < cnt && mi[f] == idxs[e]) { mw[f] += ws[e]; found = true; }
        if (!found && cnt < 3) { mi[cnt] = idxs[e]; mw[cnt] = ws[e]; ++cnt; }
      }
    }
    if (isY) {
#pragma unroll
      for (int f = 0; f < 3; ++f) { s_yoff[b][i][f] = mi[f] * 4096; s_wy[b][i][f] = mw[f] * 0.25f; }
    } else {
#pragma unroll
      for (int f = 0; f < 3; ++f) { s_xoff[b][i][f] = mi[f] * 128; s_wx[b][i][f] = mw[f]; }
    }
  }
  __syncthreads();           // drains gl_lds (vmcnt) + table writes
  const int b = t >> 3, cg = t & 7;
  const int map = slice >> 2, c0 = (slice & 3) * 64;
  const int n = grp * 32 + b;
  const char* fb = (const char*)feat + cg * 16;
  unsigned short* outp = (unsigned short*)A + (size_t)n * KTOT + map * HALF_K + c0 + cg * 8;
  for (int oy = 0; oy < 7; ++oy) {
    int yo0 = s_yoff[b][oy][0], yo1 = s_yoff[b][oy][1], yo2 = s_yoff[b][oy][2];
    float wy0 = s_wy[b][oy][0], wy1 = s_wy[b][oy][1], wy2 = s_wy[b][oy][2];
#pragma unroll
    for (int ox = 0; ox < 7; ++ox) {
      int xo0 = s_xoff[b][ox][0], xo1 = s_xoff[b][ox][1], xo2 = s_xoff[b][ox][2];
      float wx0 = s_wx[b][ox][0], wx1 = s_wx[b][ox][1], wx2 = s_wx[b][ox][2];
      short8 u00 = *(const short8*)(fb + yo0 + xo0);
      short8 u01 = *(const short8*)(fb + yo0 + xo1);
      short8 u02 = *(const short8*)(fb + yo0 + xo2);
      short8 u10 = *(const short8*)(fb + yo1 + xo0);
      short8 u11 = *(const short8*)(fb + yo1 + xo1);
      short8 u12 = *(const short8*)(fb + yo1 + xo2);
      short8 u20 = *(const short8*)(fb + yo2 + xo0);
      short8 u21 = *(const short8*)(fb + yo2 + xo1);
      short8 u22 = *(const short8*)(fb + yo2 + xo2);
      float w00 = wy0 * wx0, w01 = wy0 * wx1, w02 = wy0 * wx2;
      float w10 = wy1 * wx0, w11 = wy1 * wx1, w12 = wy1 * wx2;
      float w20 = wy2 * wx0, w21 = wy2 * wx1, w22 = wy2 * wx2;
      float a[8];
#pragma unroll
      for (int e = 0; e < 8; ++e) {
        float s = w00 * bf2f((unsigned short)u00[e]);
        s += w01 * bf2f((unsigned short)u01[e]);
        s += w02 * bf2f((unsigned short)u02[e]);
        s += w10 * bf2f((unsigned short)u10[e]);
        s += w11 * bf2f((unsigned short)u11[e]);
        s += w12 * bf2f((unsigned short)u12[e]);
        s += w20 * bf2f((unsigned short)u20[e]);
        s += w21 * bf2f((unsigned short)u21[e]);
        s += w22 * bf2f((unsigned short)u22[e]);
        a[e] = s;
      }
      short8 o;
#pragma unroll
      for (int e = 0; e < 8; ++e) o[e] = (short)f2bf(a[e]);
      *(short8*)(outp + (oy * 7 + ox) * 256) = o;
    }
  }
}

// ---------- GEMM1: 128x128 tile, BK=64, 4 waves, counted-vmcnt pipeline (round-12 exact) ----------
__global__ __launch_bounds__(256, 2) void k_gemm1(const __hip_bfloat16* __restrict__ A,
                                                  const __hip_bfloat16* __restrict__ Bt,
                                                  unsigned short* __restrict__ parts, int M) {
  __shared__ __align__(16) __hip_bfloat16 As[2][128 * 64];   // 2 x 16 KB
  __shared__ __align__(16) __hip_bfloat16 Bs[2][128 * 64];   // 2 x 16 KB  -> 64 KB total
  const int t = threadIdx.x;
  const int bid = blockIdx.x;
  const int newid = (bid & 7) * 56 + (bid >> 3);
  const int tile = newid & 31, kc = newid >> 5;
  const int row0 = (tile >> 2) * 128, col0 = (tile & 3) * 128;
  const size_t k0 = (size_t)kc * KCHUNK;

  const int srow = t >> 3;
  const int sq = (t & 7) ^ (srow & 7);
  const __hip_bfloat16* ags = A  + (size_t)(row0 + srow) * KTOT + k0 + sq * 8;
  const __hip_bfloat16* bgs = Bt + (size_t)(col0 + srow) * KTOT + k0 + sq * 8;

  const int lane = t & 63, wid = t >> 6;
  const int wm = wid >> 1, wn = wid & 1;
  const int r = lane & 15, g = lane >> 4;
  const int qs0 = ((g ^ (r & 7)) * 16);
  const int qs1 = qs0 ^ 64;
  const char* aB = (const char*)&As[0][0] + (wm * 64 + r) * 128;
  const char* bB = (const char*)&Bs[0][0] + (wn * 64 + r) * 128;

  f32x4 acc[4][4];
#pragma unroll
  for (int m = 0; m < 4; ++m)
#pragma unroll
    for (int n = 0; n < 4; ++n) acc[m][n] = (f32x4){0.f, 0.f, 0.f, 0.f};

#define STAGE(KT, BUF) do {                                             \
    const __hip_bfloat16* a_ = ags + (size_t)(KT) * 64;                 \
    const __hip_bfloat16* b_ = bgs + (size_t)(KT) * 64;                 \
    _Pragma("unroll")                                                   \
    for (int i_ = 0; i_ < 4; ++i_) {                                    \
      gl_lds16(a_ + (size_t)i_ * 32 * KTOT, &As[BUF][t * 8 + i_ * 2048]); \
      gl_lds16(b_ + (size_t)i_ * 32 * KTOT, &Bs[BUF][t * 8 + i_ * 2048]); \
    } } while (0)

#define TILE(BUF) do { const int bo_ = (BUF) * 16384;                   \
    short8 a0[4], b0[4], a1[4], b1[4];                                  \
    _Pragma("unroll")                                                   \
    for (int m_ = 0; m_ < 4; ++m_) {                                    \
      a0[m_] = *(const short8*)(aB + bo_ + m_ * 2048 + qs0);            \
      b0[m_] = *(const short8*)(bB + bo_ + m_ * 2048 + qs0);            \
    }                                                                   \
    _Pragma("unroll")                                                   \
    for (int m_ = 0; m_ < 4; ++m_) {                                    \
      a1[m_] = *(const short8*)(aB + bo_ + m_ * 2048 + qs1);            \
      b1[m_] = *(const short8*)(bB + bo_ + m_ * 2048 + qs1);            \
    }                                                                   \
    asm volatile("s_waitcnt lgkmcnt(8)" ::: "memory");                  \
    __builtin_amdgcn_sched_barrier(0);                                  \
    __builtin_amdgcn_s_setprio(1);                                      \
    _Pragma("unroll")                                                   \
    for (int m_ = 0; m_ < 4; ++m_) { _Pragma("unroll")                  \
      for (int n_ = 0; n_ < 4; ++n_)                                    \
        acc[m_][n_] = __builtin_amdgcn_mfma_f32_16x16x32_bf16(          \
            a0[m_], b0[n_], acc[m_][n_], 0, 0, 0); }                    \
    __builtin_amdgcn_s_setprio(0);                                      \
    asm volatile("s_waitcnt lgkmcnt(0)" ::: "memory");                  \
    __builtin_amdgcn_sched_barrier(0);                                  \
    __builtin_amdgcn_s_setprio(1);                                      \
    _Pragma("unroll")                                                   \
    for (int m_ = 0; m_ < 4; ++m_) { _Pragma("unroll")                  \
      for (int n_ = 0; n_ < 4; ++n_)                                    \
        acc[m_][n_] = __builtin_amdgcn_mfma_f32_16x16x32_bf16(          \
            a1[m_], b1[n_], acc[m_][n_], 0, 0, 0); }                    \
    __builtin_amdgcn_s_setprio(0);                                      \
  } while (0)

#define SB0 __builtin_amdgcn_sched_barrier(0)

  STAGE(0, 0);
  STAGE(1, 1);
  for (int kt = 0; kt < NTILE - 1; ++kt) {
    asm volatile("s_waitcnt vmcnt(8)" ::: "memory"); SB0;
    __builtin_amdgcn_s_barrier(); SB0;
    TILE(kt & 1);
    SB0;
    if (kt < NTILE - 2) {
      __builtin_amdgcn_s_barrier(); SB0;
      STAGE(kt + 2, kt & 1);
    }
  }
  asm volatile("s_waitcnt vmcnt(0)" ::: "memory"); SB0;
  __builtin_amdgcn_s_barrier(); SB0;
  TILE(1);

#undef STAGE
#undef TILE
#undef SB0

  unsigned short* P = parts + (size_t)kc * ((size_t)M * HID);
#pragma unroll
  for (int m = 0; m < 4; ++m)
#pragma unroll
    for (int n = 0; n < 4; ++n)
#pragma unroll
      for (int q = 0; q < 4; ++q) {
        int rr = row0 + wm * 64 + m * 16 + g * 4 + q;
        int cc = col0 + wn * 64 + n * 16 + r;
        P[(size_t)rr * HID + cc] = f2bf(acc[m][n][q]);
      }
}

// ---------- fused head: sum split-K partials + bias + ReLU + W2 GEMM + sigmoids ----------
__global__ __launch_bounds__(256) void k_head(const unsigned short* __restrict__ parts,
                                              const float* __restrict__ b1,
                                              const float* __restrict__ W2,
                                              const float* __restrict__ b2,
                                              float* __restrict__ out, int N) {
  __shared__ float hrow[512];
  __shared__ float part[16][17];
  const int n = blockIdx.x, t = threadIdx.x;
  if (t < 64) {
    float a[8] = {0.f, 0.f, 0.f, 0.f, 0.f, 0.f, 0.f, 0.f};
    const unsigned short* base = parts + (size_t)n * HID + t * 8;
    for (int p = 0; p < SPLITK; ++p) {
      short8 v = *(const short8*)(base + (size_t)p * ((size_t)N * HID));
#pragma unroll
      for (int e = 0; e < 8; ++e) a[e] += bf2f((unsigned short)v[e]);
    }
#pragma unroll
    for (int e = 0; e < 8; ++e) hrow[t * 8 + e] = fmaxf(a[e] + b1[t * 8 + e], 0.f);
  }
  __syncthreads();
  int j = t & 15, kc = t >> 4;
  float a = 0.f;
  if (j < 11) {
#pragma unroll
    for (int kk = 0; kk < 32; ++kk) {
      int k = kc * 32 + kk;
      a += hrow[k] * W2[k * 11 + j];
    }
  }
  part[kc][j] = a;
  __syncthreads();
  if (t < 11) {
    float sm = b2[t];
#pragma unroll
    for (int k2 = 0; k2 < 16; ++k2) sm += part[k2][t];
    if (t == 0)      out[n] = 1.f / (1.f + expf(-sm));
    else if (t == 1) out[N + n] = 1.f / (1.f + expf(-sm));
    else if (t < 6)  out[2 * N + n * 4 + (t - 2)] = sm;
    else if (t < 10) out[6 * N + n * 4 + (t - 6)] = sm;
    else             out[10 * N + n] = 1.f / (1.f + expf(-sm));
  }
}

extern "C" void kernel_launch(void* const* d_in, const int* in_sizes, int n_in,
                              void* d_out, int out_size, void* d_ws, size_t ws_size,
                              hipStream_t stream) {
  const float* feats1 = (const float*)d_in[0];
  const float* feats2 = (const float*)d_in[1];
  const float* props  = (const float*)d_in[2];
  const float* W1     = (const float*)d_in[3];
  const float* b1     = (const float*)d_in[4];
  const float* W2     = (const float*)d_in[5];
  const float* b2     = (const float*)d_in[6];
  float* out = (float*)d_out;
  const int N = in_sizes[2] / 4;   // 1024

  char* ws = (char*)d_ws;
  __hip_bfloat16* fts = (__hip_bfloat16*)ws;                       // 1 MB [map][cs][cell][64]
  __hip_bfloat16* Abuf = (__hip_bfloat16*)(ws + (1u << 20));       // 49 MB
  size_t offW1t = (1u << 20) + (size_t)N * KTOT * 2;
  __hip_bfloat16* W1t = (__hip_bfloat16*)(ws + offW1t);            // 24.5 MB
  size_t offParts = offW1t + (size_t)HID * KTOT * 2;
  unsigned short* parts = (unsigned short*)(ws + offParts);        // 14.7 MB bf16 [sp][row][col]

  k_tfeat<<<dim3(4, 16, 2), 256, 0, stream>>>(feats1, feats2, fts);
  k_tw1<<<dim3(32, 49, 2), 256, 0, stream>>>(W1, W1t);
  k_roi<<<dim3(256), 256, 0, stream>>>(fts, props, Abuf);
  k_gemm1<<<dim3(32 * SPLITK), 256, 0, stream>>>(Abuf, W1t, parts, N);
  k_head<<<dim3(N), 256, 0, stream>>>(parts, b1, W2, b2, out, N);
}

// Round 19
// 80.208 us; speedup vs baseline: 1.0114x; 1.0114x over previous
//
#include <hip/hip_runtime.h>
#include <hip/hip_bf16.h>

#define KTOT   25088          // 2 * 256 * 49
#define HALF_K 12544
#define HID    512
#define SPLITK 14
#define KCHUNK (KTOT/SPLITK)  // 1792 = 28 * 64
#define NTILE  28             // BK=64 tiles per k-chunk

typedef __attribute__((ext_vector_type(8))) short short8;
typedef __attribute__((ext_vector_type(4))) float f32x4;

__device__ __forceinline__ unsigned short f2bf(float x) {
  __hip_bfloat16 h = __float2bfloat16(x);
  return *reinterpret_cast<unsigned short*>(&h);
}
__device__ __forceinline__ float bf2f(unsigned short u) {
  return __uint_as_float((unsigned)u << 16);
}

// ---------- feats [C,H,W] fp32 -> ft bf16 [map][y*32+x][c] ----------
__global__ __launch_bounds__(256) void k_tfeat(const float* __restrict__ f1,
                                               const float* __restrict__ f2,
                                               __hip_bfloat16* __restrict__ ft) {
  __shared__ float tile[64][65];
  const int ct = blockIdx.x, yxt = blockIdx.y, map = blockIdx.z;
  const float* src = map ? f2 : f1;
  const int t = threadIdx.x, t4 = t >> 6, tl = t & 63;
#pragma unroll
  for (int pass = 0; pass < 16; ++pass) {
    int cl = pass * 4 + t4;
    tile[cl][tl] = src[(ct * 64 + cl) * 1024 + yxt * 64 + tl];
  }
  __syncthreads();
#pragma unroll
  for (int pass = 0; pass < 16; ++pass) {
    int yl = pass * 4 + t4;
    ft[(size_t)map * 262144 + (size_t)(yxt * 64 + yl) * 256 + ct * 64 + tl] =
        __float2bfloat16(tile[tl][yl]);
  }
}

// ---------- fused prep: tw1 (HBM-bound) + roi (L2-bound) interleaved for overlap ----------
// grid 4928 = 448 groups * 11; pos<4 -> roi (1792 blocks), else tw1 (3136 blocks)
__global__ __launch_bounds__(256) void k_prep(const float* __restrict__ W1,
                                              __hip_bfloat16* __restrict__ W1t,
                                              const __hip_bfloat16* __restrict__ ft,
                                              const float* __restrict__ props,
                                              __hip_bfloat16* __restrict__ A) {
  __shared__ float tile[64][65];
  __shared__ int   s_ny[4];
  __shared__ int   s_yoff[4][4];
  __shared__ float s_wy[4][4];
  __shared__ int   s_nx[4][7];
  __shared__ int   s_xoff[4][7][4];
  __shared__ float s_wx[4][7][4];
  const int t = threadIdx.x;
  const int grp = blockIdx.x / 11, pos = blockIdx.x % 11;
  if (pos >= 4) {
    // ---- tw1 path: W1 [25088][512] -> W1t bf16 [512][25088'] ----
    const int ti = grp * 7 + (pos - 4);          // 0..3135
    const int bx = ti & 31;
    const int p = (ti >> 5) % 49;
    const int map = ti / 1568;
    const int ct = bx & 3, jt = bx >> 2;
    const int t4 = t >> 6, tl = t & 63;
#pragma unroll
    for (int pass = 0; pass < 16; ++pass) {
      int cl = pass * 4 + t4;
      int c = ct * 64 + cl;
      size_t krow = (size_t)map * HALF_K + (size_t)c * 49 + p;
      tile[cl][tl] = W1[krow * HID + jt * 64 + tl];
    }
    __syncthreads();
#pragma unroll
    for (int pass = 0; pass < 16; ++pass) {
      int jl = pass * 4 + t4;
      int j = jt * 64 + jl;
      W1t[(size_t)j * KTOT + (size_t)map * HALF_K + p * 256 + ct * 64 + tl] =
          __float2bfloat16(tile[tl][jl]);
    }
    return;
  }
  // ---- roi path: separable merged-corner gather, 16B loads ----
  const int ri = grp * 4 + pos;                  // 0..1791
  const int nb = (ri & 255) * 4;
  const int oy = ri >> 8;
  const float sc = 1.0f / 32.0f;
  if (t < 32) {
    const int b = t >> 3, j = t & 7;
    const int n = nb + b;
    float bx1 = props[n * 4 + 0] * sc, by1 = props[n * 4 + 1] * sc;
    float bx2 = props[n * 4 + 2] * sc, by2 = props[n * 4 + 3] * sc;
    float bw = fmaxf(bx2 - bx1, 1.f) * (1.f / 7.f);
    float bh = fmaxf(by2 - by1, 1.f) * (1.f / 7.f);
    const bool isY = (j == 0);
    const int i = isY ? oy : (j - 1);
    const float start = isY ? by1 : bx1;
    const float bs = isY ? bh : bw;
    int idxs[4]; float ws[4];
#pragma unroll
    for (int ssub = 0; ssub < 2; ++ssub) {
      float o = start + (float)i * bs + ((float)ssub + 0.5f) * bs * 0.5f;
      float v = (o >= -1.f && o <= 32.f) ? 1.f : 0.f;
      float oc = fminf(fmaxf(o, 0.f), 31.f);
      int i0 = (int)oc;
      int i1 = min(i0 + 1, 31);
      float l = oc - (float)i0;
      idxs[ssub * 2 + 0] = i0; ws[ssub * 2 + 0] = v * (1.f - l);
      idxs[ssub * 2 + 1] = i1; ws[ssub * 2 + 1] = v * l;
    }
    int mi[4]; float mw[4]; int cnt = 0;
#pragma unroll
    for (int e = 0; e < 4; ++e) {
      if (ws[e] != 0.f) {
        bool found = false;
#pragma unroll
        for (int f = 0; f < 4; ++f)
          if (f < cnt && mi[f] == idxs[e]) { mw[f] += ws[e]; found = true; }
        if (!found) { mi[cnt] = idxs[e]; mw[cnt] = ws[e]; ++cnt; }
      }
    }
#pragma unroll
    for (int f = 0; f < 4; ++f) if (f >= cnt) { mi[f] = 0; mw[f] = 0.f; }
    if (isY) {
      s_ny[b] = cnt;
#pragma unroll
      for (int f = 0; f < 4; ++f) { s_yoff[b][f] = mi[f] * 16384; s_wy[b][f] = mw[f] * 0.25f; }
    } else {
      s_nx[b][j - 1] = cnt;
#pragma unroll
      for (int f = 0; f < 4; ++f) { s_xoff[b][j - 1][f] = mi[f] * 512; s_wx[b][j - 1][f] = mw[f]; }
    }
  }
  __syncthreads();
  const int b = t >> 6, map = (t >> 5) & 1, q = t & 31;
  const char* fb = (const char*)ft;
  const unsigned qoff = (unsigned)(map * 524288 + q * 16);
  const int n = nb + b;
  const int ny = s_ny[b];
  unsigned ybase[4]; float wyr[4];
#pragma unroll
  for (int yy = 0; yy < 4; ++yy) {
    ybase[yy] = qoff + (unsigned)s_yoff[b][yy];
    wyr[yy] = s_wy[b][yy];
  }
  __hip_bfloat16* outp = A + (size_t)n * KTOT + map * HALF_K + q * 8 + oy * 7 * 256;
  for (int bl = 0; bl < 7; ++bl) {
    const int nx = s_nx[b][bl];
    float a[8] = {0.f, 0.f, 0.f, 0.f, 0.f, 0.f, 0.f, 0.f};
    for (int xx = 0; xx < nx; ++xx) {
      const unsigned xo = (unsigned)s_xoff[b][bl][xx];
      const float wxv = s_wx[b][bl][xx];
      for (int yy = 0; yy < ny; ++yy) {
        short8 u = *(const short8*)(fb + (ybase[yy] + xo));
        float w = wyr[yy] * wxv;
#pragma unroll
        for (int e = 0; e < 8; ++e) a[e] += w * bf2f((unsigned short)u[e]);
      }
    }
    short8 o;
#pragma unroll
    for (int e = 0; e < 8; ++e) o[e] = (short)f2bf(a[e]);
    *(short8*)(outp + bl * 256) = o;
  }
}

// ---------- GEMM1: 128x128 tile, BK=64, 4 waves, counted-vmcnt pipeline (round-12 exact) ----------
__device__ __forceinline__ void gl_lds16(const __hip_bfloat16* g, __hip_bfloat16* l) {
  __builtin_amdgcn_global_load_lds((const __attribute__((address_space(1))) void*)g,
                                   (__attribute__((address_space(3))) void*)l, 16, 0, 0);
}

__global__ __launch_bounds__(256, 2) void k_gemm1(const __hip_bfloat16* __restrict__ A,
                                                  const __hip_bfloat16* __restrict__ Bt,
                                                  unsigned short* __restrict__ parts, int M) {
  __shared__ __align__(16) __hip_bfloat16 As[2][128 * 64];   // 2 x 16 KB
  __shared__ __align__(16) __hip_bfloat16 Bs[2][128 * 64];   // 2 x 16 KB  -> 64 KB total
  const int t = threadIdx.x;
  const int bid = blockIdx.x;
  const int newid = (bid & 7) * 56 + (bid >> 3);
  const int tile = newid & 31, kc = newid >> 5;
  const int row0 = (tile >> 2) * 128, col0 = (tile & 3) * 128;
  const size_t k0 = (size_t)kc * KCHUNK;

  const int srow = t >> 3;
  const int sq = (t & 7) ^ (srow & 7);
  const __hip_bfloat16* ags = A  + (size_t)(row0 + srow) * KTOT + k0 + sq * 8;
  const __hip_bfloat16* bgs = Bt + (size_t)(col0 + srow) * KTOT + k0 + sq * 8;

  const int lane = t & 63, wid = t >> 6;
  const int wm = wid >> 1, wn = wid & 1;
  const int r = lane & 15, g = lane >> 4;
  const int qs0 = ((g ^ (r & 7)) * 16);
  const int qs1 = qs0 ^ 64;
  const char* aB = (const char*)&As[0][0] + (wm * 64 + r) * 128;
  const char* bB = (const char*)&Bs[0][0] + (wn * 64 + r) * 128;

  f32x4 acc[4][4];
#pragma unroll
  for (int m = 0; m < 4; ++m)
#pragma unroll
    for (int n = 0; n < 4; ++n) acc[m][n] = (f32x4){0.f, 0.f, 0.f, 0.f};

#define STAGE(KT, BUF) do {                                             \
    const __hip_bfloat16* a_ = ags + (size_t)(KT) * 64;                 \
    const __hip_bfloat16* b_ = bgs + (size_t)(KT) * 64;                 \
    _Pragma("unroll")                                                   \
    for (int i_ = 0; i_ < 4; ++i_) {                                    \
      gl_lds16(a_ + (size_t)i_ * 32 * KTOT, &As[BUF][t * 8 + i_ * 2048]); \
      gl_lds16(b_ + (size_t)i_ * 32 * KTOT, &Bs[BUF][t * 8 + i_ * 2048]); \
    } } while (0)

#define TILE(BUF) do { const int bo_ = (BUF) * 16384;                   \
    short8 a0[4], b0[4], a1[4], b1[4];                                  \
    _Pragma("unroll")                                                   \
    for (int m_ = 0; m_ < 4; ++m_) {                                    \
      a0[m_] = *(const short8*)(aB + bo_ + m_ * 2048 + qs0);            \
      b0[m_] = *(const short8*)(bB + bo_ + m_ * 2048 + qs0);            \
    }                                                                   \
    _Pragma("unroll")                                                   \
    for (int m_ = 0; m_ < 4; ++m_) {                                    \
      a1[m_] = *(const short8*)(aB + bo_ + m_ * 2048 + qs1);            \
      b1[m_] = *(const short8*)(bB + bo_ + m_ * 2048 + qs1);            \
    }                                                                   \
    asm volatile("s_waitcnt lgkmcnt(8)" ::: "memory");                  \
    __builtin_amdgcn_sched_barrier(0);                                  \
    __builtin_amdgcn_s_setprio(1);                                      \
    _Pragma("unroll")                                                   \
    for (int m_ = 0; m_ < 4; ++m_) { _Pragma("unroll")                  \
      for (int n_ = 0; n_ < 4; ++n_)                                    \
        acc[m_][n_] = __builtin_amdgcn_mfma_f32_16x16x32_bf16(          \
            a0[m_], b0[n_], acc[m_][n_], 0, 0, 0); }                    \
    __builtin_amdgcn_s_setprio(0);                                      \
    asm volatile("s_waitcnt lgkmcnt(0)" ::: "memory");                  \
    __builtin_amdgcn_sched_barrier(0);                                  \
    __builtin_amdgcn_s_setprio(1);                                      \
    _Pragma("unroll")                                                   \
    for (int m_ = 0; m_ < 4; ++m_) { _Pragma("unroll")                  \
      for (int n_ = 0; n_ < 4; ++n_)                                    \
        acc[m_][n_] = __builtin_amdgcn_mfma_f32_16x16x32_bf16(          \
            a1[m_], b1[n_], acc[m_][n_], 0, 0, 0); }                    \
    __builtin_amdgcn_s_setprio(0);                                      \
  } while (0)

#define SB0 __builtin_amdgcn_sched_barrier(0)

  STAGE(0, 0);
  STAGE(1, 1);
  for (int kt = 0; kt < NTILE - 1; ++kt) {
    asm volatile("s_waitcnt vmcnt(8)" ::: "memory"); SB0;
    __builtin_amdgcn_s_barrier(); SB0;
    TILE(kt & 1);
    SB0;
    if (kt < NTILE - 2) {
      __builtin_amdgcn_s_barrier(); SB0;
      STAGE(kt + 2, kt & 1);
    }
  }
  asm volatile("s_waitcnt vmcnt(0)" ::: "memory"); SB0;
  __builtin_amdgcn_s_barrier(); SB0;
  TILE(1);

#undef STAGE
#undef TILE
#undef SB0

  unsigned short* P = parts + (size_t)kc * ((size_t)M * HID);
#pragma unroll
  for (int m = 0; m < 4; ++m)
#pragma unroll
    for (int n = 0; n < 4; ++n)
#pragma unroll
      for (int q = 0; q < 4; ++q) {
        int rr = row0 + wm * 64 + m * 16 + g * 4 + q;
        int cc = col0 + wn * 64 + n * 16 + r;
        P[(size_t)rr * HID + cc] = f2bf(acc[m][n][q]);
      }
}

// ---------- fused head: sum split-K partials + bias + ReLU + W2 GEMM + sigmoids ----------
__global__ __launch_bounds__(256) void k_head(const unsigned short* __restrict__ parts,
                                              const float* __restrict__ b1,
                                              const float* __restrict__ W2,
                                              const float* __restrict__ b2,
                                              float* __restrict__ out, int N) {
  __shared__ float hrow[512];
  __shared__ float part[16][17];
  const int n = blockIdx.x, t = threadIdx.x;
  if (t < 64) {
    float a[8] = {0.f, 0.f, 0.f, 0.f, 0.f, 0.f, 0.f, 0.f};
    const unsigned short* base = parts + (size_t)n * HID + t * 8;
    for (int p = 0; p < SPLITK; ++p) {
      short8 v = *(const short8*)(base + (size_t)p * ((size_t)N * HID));
#pragma unroll
      for (int e = 0; e < 8; ++e) a[e] += bf2f((unsigned short)v[e]);
    }
#pragma unroll
    for (int e = 0; e < 8; ++e) hrow[t * 8 + e] = fmaxf(a[e] + b1[t * 8 + e], 0.f);
  }
  __syncthreads();
  int j = t & 15, kc = t >> 4;
  float a = 0.f;
  if (j < 11) {
#pragma unroll
    for (int kk = 0; kk < 32; ++kk) {
      int k = kc * 32 + kk;
      a += hrow[k] * W2[k * 11 + j];
    }
  }
  part[kc][j] = a;
  __syncthreads();
  if (t < 11) {
    float sm = b2[t];
#pragma unroll
    for (int k2 = 0; k2 < 16; ++k2) sm += part[k2][t];
    if (t == 0)      out[n] = 1.f / (1.f + expf(-sm));
    else if (t == 1) out[N + n] = 1.f / (1.f + expf(-sm));
    else if (t < 6)  out[2 * N + n * 4 + (t - 2)] = sm;
    else if (t < 10) out[6 * N + n * 4 + (t - 6)] = sm;
    else             out[10 * N + n] = 1.f / (1.f + expf(-sm));
  }
}

extern "C" void kernel_launch(void* const* d_in, const int* in_sizes, int n_in,
                              void* d_out, int out_size, void* d_ws, size_t ws_size,
                              hipStream_t stream) {
  const float* feats1 = (const float*)d_in[0];
  const float* feats2 = (const float*)d_in[1];
  const float* props  = (const float*)d_in[2];
  const float* W1     = (const float*)d_in[3];
  const float* b1     = (const float*)d_in[4];
  const float* W2     = (const float*)d_in[5];
  const float* b2     = (const float*)d_in[6];
  float* out = (float*)d_out;
  const int N = in_sizes[2] / 4;   // 1024

  char* ws = (char*)d_ws;
  __hip_bfloat16* ft = (__hip_bfloat16*)ws;                        // 1 MB
  __hip_bfloat16* Abuf = (__hip_bfloat16*)(ws + (1u << 20));       // 49 MB
  size_t offW1t = (1u << 20) + (size_t)N * KTOT * 2;
  __hip_bfloat16* W1t = (__hip_bfloat16*)(ws + offW1t);            // 24.5 MB
  size_t offParts = offW1t + (size_t)HID * KTOT * 2;
  unsigned short* parts = (unsigned short*)(ws + offParts);        // 14.7 MB bf16 [sp][row][col]

  k_tfeat<<<dim3(4, 16, 2), 256, 0, stream>>>(feats1, feats2, ft);
  k_prep<<<dim3(4928), 256, 0, stream>>>(W1, W1t, ft, props, Abuf);
  k_gemm1<<<dim3(32 * SPLITK), 256, 0, stream>>>(Abuf, W1t, parts, N);
  k_head<<<dim3(N), 256, 0, stream>>>(parts, b1, W2, b2, out, N);
}